// Round 9
// baseline (1651.736 us; speedup 1.0000x reference)
//
#include <hip/hip_runtime.h>
#include <math.h>

#define NTOK 16384   // 128 sequences * 128 steps

typedef __attribute__((ext_vector_type(8))) short bf16x8;
typedef __attribute__((ext_vector_type(4))) float f32x4;

__device__ __forceinline__ float geluf(float x){
    return 0.5f*x*(1.0f+erff(x*0.70710678118654752f));
}
__device__ __forceinline__ float siluf(float x){
    return x/(1.0f+__expf(-x));
}
__device__ __forceinline__ float softplusf(float x){
    return (x>20.0f)? x : log1pf(__expf(x));
}
__device__ __forceinline__ void split_bf16(float x, unsigned short& h, unsigned short& l){
    union { float f; unsigned u; } c; c.f = x;
    h = (unsigned short)(c.u >> 16);
    union { unsigned u; float f; } hf; hf.u = c.u & 0xffff0000u;
    union { float f; unsigned u; } rc; rc.f = x - hf.f;
    l = (unsigned short)(rc.u >> 16);
}

// ---------------------------------------------------------------------------
// enc1 conv (CI=1), original structure - cheap, leave alone.
template<bool GELU_OUT>
__global__ __launch_bounds__(256) void conv3x3_kernel(
    const float* __restrict__ in, const float* __restrict__ wgt,
    const float* __restrict__ bias, float* __restrict__ out,
    int CI, int CO)
{
    __shared__ float tile[18][68];
    const int tx = threadIdx.x & 15;
    const int ty = threadIdx.x >> 4;
    const int w0 = blockIdx.x * 64;
    const int h0 = blockIdx.y * 16;
    const int cog = blockIdx.z * 8;

    float acc[8][4];
    #pragma unroll
    for (int i=0;i<8;i++){
        float b = (cog+i < CO) ? bias[cog+i] : 0.f;
        #pragma unroll
        for (int j=0;j<4;j++) acc[i][j] = b;
    }

    for (int ci=0; ci<CI; ci++){
        const float* inp = in + ci*16384;
        for (int e = threadIdx.x; e < 18*66; e += 256){
            int r = e/66, cc = e - r*66;
            int hh = h0 - 1 + r, ww = w0 - 1 + cc;
            float v = 0.f;
            if ((unsigned)hh < 128u && (unsigned)ww < 128u) v = inp[hh*128+ww];
            tile[r][cc] = v;
        }
        __syncthreads();
        float rin[3][8];
        #pragma unroll
        for (int r=0;r<3;r++){
            float4 a = *(const float4*)&tile[ty+r][tx*4];
            float4 b = *(const float4*)&tile[ty+r][tx*4+4];
            rin[r][0]=a.x; rin[r][1]=a.y; rin[r][2]=a.z; rin[r][3]=a.w;
            rin[r][4]=b.x; rin[r][5]=b.y; rin[r][6]=b.z; rin[r][7]=b.w;
        }
        #pragma unroll
        for (int co=0; co<8; co++){
            if (cog+co < CO) {
                const float* wp = wgt + ((cog+co)*CI + ci)*9;
                #pragma unroll
                for (int r=0;r<3;r++){
                    #pragma unroll
                    for (int dx=0;dx<3;dx++){
                        float wv = wp[r*3+dx];
                        #pragma unroll
                        for (int j=0;j<4;j++)
                            acc[co][j] = fmaf(wv, rin[r][j+dx], acc[co][j]);
                    }
                }
            }
        }
        __syncthreads();
    }
    const int h = h0 + ty;
    const int wbase = w0 + tx*4;
    #pragma unroll
    for (int co=0; co<8; co++){
        if (cog+co < CO){
            float t0 = acc[co][0], t1 = acc[co][1], t2 = acc[co][2], t3 = acc[co][3];
            if (GELU_OUT){ t0=geluf(t0); t1=geluf(t1); t2=geluf(t2); t3=geluf(t3); }
            *(float4*)&out[(cog+co)*16384 + h*128 + wbase] = make_float4(t0,t1,t2,t3);
        }
    }
}

// ---------------------------------------------------------------------------
// weight split prepass: wgt [128co][128ci][3][3] f32 -> hi/lo bf16 in
// fragment-major layout [t][cog8][chunk4][kg4][lr16][j8].
__global__ __launch_bounds__(256) void wsplit_kernel(
    const float* __restrict__ wgt, unsigned short* __restrict__ whi,
    unsigned short* __restrict__ wlo)
{
    int e = blockIdx.x*256 + threadIdx.x;   // < 147456
    int ci = e & 127, co = (e >> 7) & 127, t = e >> 14;
    float v = wgt[((co<<7)|ci)*9 + t];
    unsigned short h, l; split_bf16(v, h, l);
    int cog = co >> 4, lr = co & 15;
    int chk = ci >> 5, kg = (ci >> 3) & 3, j = ci & 7;
    int o = ((((t*8 + cog)*4 + chk)*4 + kg)*16 + lr)*8 + j;
    whi[o] = h; wlo[o] = l;
}

// ---------------------------------------------------------------------------
// conv2d 3x3 as 9-tap split-bf16 MFMA GEMM. CI=CO=128 fixed.
template<bool GELU_OUT>
__global__ __launch_bounds__(256) void conv_mfma_kernel(
    const float* __restrict__ in, const unsigned short* __restrict__ whi,
    const unsigned short* __restrict__ wlo, const float* __restrict__ bias,
    float* __restrict__ out)
{
    __shared__ unsigned short sHi[6*20*40], sLo[6*20*40];
    const int tid  = threadIdx.x;
    const int wave = tid >> 6;
    const int lane = tid & 63;
    const int wr   = wave >> 1;
    const int wc   = wave & 1;
    const int lr   = lane & 15;
    const int kg   = lane >> 4;
    const int w0   = blockIdx.x * 16;
    const int h0   = blockIdx.y * 4;
    const int cogz = blockIdx.z * 4;

    f32x4 acc[2][2];
    #pragma unroll
    for (int cg=0;cg<2;cg++)
        #pragma unroll
        for (int pg=0;pg<2;pg++)
            acc[cg][pg] = (f32x4){0.f,0.f,0.f,0.f};

    for (int ch = 0; ch < 4; ch++){
        const int cc0 = ch*32;
        for (int e = tid; e < 3456; e += 256){
            int cil = e / 108;
            int rem = e - cil*108;
            int hl  = rem / 18;
            int wl  = rem - hl*18;
            int hh = h0 - 1 + hl, ww = w0 - 1 + wl;
            float v = 0.f;
            if ((unsigned)hh < 128u && (unsigned)ww < 128u)
                v = in[(size_t)(cc0+cil)*16384 + hh*128 + ww];
            unsigned short hi, lo; split_bf16(v, hi, lo);
            int o = (hl*20 + wl)*40 + cil;
            sHi[o] = hi; sLo[o] = lo;
        }
        __syncthreads();
        #pragma unroll
        for (int dy=0; dy<3; dy++){
            #pragma unroll
            for (int dx=0; dx<3; dx++){
                const int t = dy*3+dx;
                bf16x8 ah[2], al[2], bh[2], bl[2];
                #pragma unroll
                for (int cg=0; cg<2; cg++){
                    int cog = cogz + wr*2 + cg;
                    size_t off = ((size_t)(((t*8 + cog)*4 + ch)*4 + kg)*16 + lr)*8;
                    ah[cg] = *(const bf16x8*)&whi[off];
                    al[cg] = *(const bf16x8*)&wlo[off];
                }
                #pragma unroll
                for (int pg=0; pg<2; pg++){
                    int g = wc*2 + pg;
                    int o = ((g+dy)*20 + lr + dx)*40 + kg*8;
                    bh[pg] = *(const bf16x8*)&sHi[o];
                    bl[pg] = *(const bf16x8*)&sLo[o];
                }
                #pragma unroll
                for (int cg=0; cg<2; cg++){
                    #pragma unroll
                    for (int pg=0; pg<2; pg++){
                        acc[cg][pg] = __builtin_amdgcn_mfma_f32_16x16x32_bf16(ah[cg], bh[pg], acc[cg][pg], 0,0,0);
                        acc[cg][pg] = __builtin_amdgcn_mfma_f32_16x16x32_bf16(ah[cg], bl[pg], acc[cg][pg], 0,0,0);
                        acc[cg][pg] = __builtin_amdgcn_mfma_f32_16x16x32_bf16(al[cg], bh[pg], acc[cg][pg], 0,0,0);
                    }
                }
            }
        }
        __syncthreads();
    }
    #pragma unroll
    for (int cg=0; cg<2; cg++){
        #pragma unroll
        for (int pg=0; pg<2; pg++){
            int h = h0 + wc*2 + pg;
            int w = w0 + lr;
            #pragma unroll
            for (int r=0; r<4; r++){
                int co = (cogz + wr*2 + cg)*16 + kg*4 + r;
                float v = acc[cg][pg][r] + bias[co];
                if (GELU_OUT) v = geluf(v);
                out[(size_t)co*16384 + h*128 + w] = v;
            }
        }
    }
}

// ---------------------------------------------------------------------------
// CO=1 conv (pred2). grid 64 blocks, block = 2 h-rows x 128 w.
__global__ __launch_bounds__(256) void conv3x3_co1_kernel(
    const float* __restrict__ in, const float* __restrict__ wgt,
    const float* __restrict__ bias, float* __restrict__ out, int CI)
{
    __shared__ float tile[16][4][128];
    const int h0 = blockIdx.x*2;
    const int hl = threadIdx.x >> 7;      // 0..1
    const int w  = threadIdx.x & 127;
    float acc = bias[0];
    for (int cc0 = 0; cc0 < CI; cc0 += 16){
        for (int e = threadIdx.x; e < 2048; e += 256){
            int c4 = e & 31, r = (e>>5)&3, ci = e>>7;
            int hh = h0 - 1 + r;
            float4 v = make_float4(0.f,0.f,0.f,0.f);
            if ((unsigned)hh < 128u)
                v = *(const float4*)&in[(size_t)(cc0+ci)*16384 + hh*128 + c4*4];
            *(float4*)&tile[ci][r][c4*4] = v;
        }
        __syncthreads();
        #pragma unroll 4
        for (int ci=0; ci<16; ci++){
            float w_s[9];
            #pragma unroll
            for (int k=0;k<9;k++) w_s[k] = wgt[(size_t)(cc0+ci)*9 + k];
            #pragma unroll
            for (int r=0;r<3;r++){
                #pragma unroll
                for (int dx=0;dx<3;dx++){
                    int col = w + dx - 1;
                    float x = ((unsigned)col < 128u) ? tile[ci][hl+r][col] : 0.f;
                    acc = fmaf(w_s[r*3+dx], x, acc);
                }
            }
        }
        __syncthreads();
    }
    out[(size_t)(h0+hl)*128 + w] = acc;
}

// ---------------------------------------------------------------------------
// Split-bf16 MFMA GEMM: C[M,N] = A[M,K] * W[N,K]^T in ~fp32 precision.
__global__ __launch_bounds__(256) void gemm_mfma_kernel(
    const float* __restrict__ A, const float* __restrict__ W,
    float* __restrict__ C, int M, int N, int K)
{
    __shared__ unsigned short Ah[64*48], Al[64*48], Bh[64*48], Bl[64*48];
    const int tid  = threadIdx.x;
    const int wave = tid >> 6;
    const int lane = tid & 63;
    const int wr   = wave >> 1;
    const int wc   = wave & 1;
    const int lrow = lane & 15;
    const int kg   = lane >> 4;

    const int m0 = blockIdx.x * 64;
    const int n0 = blockIdx.y * 64;

    f32x4 acc[2][2];
    #pragma unroll
    for (int mi=0;mi<2;mi++)
        #pragma unroll
        for (int ni=0;ni<2;ni++)
            acc[mi][ni] = (f32x4){0.f,0.f,0.f,0.f};

    for (int k0 = 0; k0 < K; k0 += 32){
        #pragma unroll
        for (int it=0; it<2; it++){
            int idx = tid + it*256;
            int r = idx >> 3, c4 = idx & 7;
            float4 v = *(const float4*)&A[(size_t)(m0+r)*K + k0 + c4*4];
            unsigned short h[4], l[4];
            split_bf16(v.x, h[0], l[0]);
            split_bf16(v.y, h[1], l[1]);
            split_bf16(v.z, h[2], l[2]);
            split_bf16(v.w, h[3], l[3]);
            *(uint2*)&Ah[r*48 + c4*4] = make_uint2(h[0]|((unsigned)h[1]<<16), h[2]|((unsigned)h[3]<<16));
            *(uint2*)&Al[r*48 + c4*4] = make_uint2(l[0]|((unsigned)l[1]<<16), l[2]|((unsigned)l[3]<<16));
        }
        #pragma unroll
        for (int it=0; it<2; it++){
            int idx = tid + it*256;
            int r = idx >> 3, c4 = idx & 7;
            float4 v = make_float4(0.f,0.f,0.f,0.f);
            if (n0 + r < N) v = *(const float4*)&W[(size_t)(n0+r)*K + k0 + c4*4];
            unsigned short h[4], l[4];
            split_bf16(v.x, h[0], l[0]);
            split_bf16(v.y, h[1], l[1]);
            split_bf16(v.z, h[2], l[2]);
            split_bf16(v.w, h[3], l[3]);
            *(uint2*)&Bh[r*48 + c4*4] = make_uint2(h[0]|((unsigned)h[1]<<16), h[2]|((unsigned)h[3]<<16));
            *(uint2*)&Bl[r*48 + c4*4] = make_uint2(l[0]|((unsigned)l[1]<<16), l[2]|((unsigned)l[3]<<16));
        }
        __syncthreads();

        bf16x8 fah[2], fal[2], fbh[2], fbl[2];
        #pragma unroll
        for (int mi=0;mi<2;mi++){
            int row = (wr*2+mi)*16 + lrow;
            fah[mi] = *(const bf16x8*)&Ah[row*48 + kg*8];
            fal[mi] = *(const bf16x8*)&Al[row*48 + kg*8];
        }
        #pragma unroll
        for (int ni=0;ni<2;ni++){
            int row = (wc*2+ni)*16 + lrow;
            fbh[ni] = *(const bf16x8*)&Bh[row*48 + kg*8];
            fbl[ni] = *(const bf16x8*)&Bl[row*48 + kg*8];
        }
        #pragma unroll
        for (int mi=0;mi<2;mi++){
            #pragma unroll
            for (int ni=0;ni<2;ni++){
                acc[mi][ni] = __builtin_amdgcn_mfma_f32_16x16x32_bf16(fah[mi], fbh[ni], acc[mi][ni], 0,0,0);
                acc[mi][ni] = __builtin_amdgcn_mfma_f32_16x16x32_bf16(fah[mi], fbl[ni], acc[mi][ni], 0,0,0);
                acc[mi][ni] = __builtin_amdgcn_mfma_f32_16x16x32_bf16(fal[mi], fbh[ni], acc[mi][ni], 0,0,0);
            }
        }
        __syncthreads();
    }
    #pragma unroll
    for (int mi=0;mi<2;mi++){
        #pragma unroll
        for (int ni=0;ni<2;ni++){
            int n = n0 + (wc*2+ni)*16 + lrow;
            if (n < N){
                #pragma unroll
                for (int r=0;r<4;r++){
                    int m = m0 + (wr*2+mi)*16 + kg*4 + r;
                    C[(size_t)m*N + n] = acc[mi][ni][r];
                }
            }
        }
    }
}

// ---------------------------------------------------------------------------
// depthwise causal conv1d (k=4) + silu.  xz [NTOK,512] (xs = cols 0..255)
__global__ __launch_bounds__(256) void conv1d_silu_kernel(
    const float* __restrict__ xz, const float* __restrict__ cw,
    const float* __restrict__ cb, float* __restrict__ U)
{
    const int m = blockIdx.x;
    const int d = threadIdx.x;
    const int t = m & 127;
    float4 w4 = *(const float4*)&cw[d*4];
    float wj[4] = {w4.x, w4.y, w4.z, w4.w};
    float s = cb[d];
    #pragma unroll
    for (int j=0;j<4;j++){
        int tt = t - 3 + j;
        if (tt >= 0) s = fmaf(wj[j], xz[(size_t)(m - 3 + j)*512 + d], s);
    }
    U[(size_t)m*256 + d] = siluf(s);
}

// ---------------------------------------------------------------------------
// fused scan with 4-deep register prefetch ring. grid (4,128), 64 thr.
// Each iter consumes stage k and refills it with t+4's u/z/proj row; 48
// outstanding loads/thread cover ~900cy HBM latency (1-deep only covered
// ~250cy -> 85us latency-bound, round 8). Static stage indices (no dynamic
// indexing -> stays in VGPRs). Clamped prefetch: t+4 read of row 127 always
// precedes this thread's t=127 write, so no hazard.
__global__ __launch_bounds__(64) void scan_fused_kernel(
    const float* __restrict__ xz, float* __restrict__ U,
    const float* __restrict__ proj, const float* __restrict__ dtw,
    const float* __restrict__ dtb, const float* __restrict__ Alog,
    const float* __restrict__ Dp)
{
    const int b = blockIdx.y;
    const int d = blockIdx.x*64 + threadIdx.x;
    float A[16], h[16];
    #pragma unroll
    for (int s=0;s<16;s++){ A[s] = -__expf(Alog[d*16+s]); h[s]=0.f; }
    float4 dw0 = *(const float4*)&dtw[d*8];
    float4 dw1 = *(const float4*)&dtw[d*8+4];
    const float dtbv = dtb[d];
    const float Dv = Dp[d];
    const int m0 = b*128;

    float uvp[4], zvp[4];
    float4 Pp[4][10];
    #pragma unroll
    for (int k=0;k<4;k++){
        int m = m0 + k;
        uvp[k] = U[(size_t)m*256 + d];
        zvp[k] = xz[(size_t)m*512 + 256 + d];
        #pragma unroll
        for (int q=0;q<10;q++) Pp[k][q] = *(const float4*)&proj[(size_t)m*40 + q*4];
    }

    for (int t0=0; t0<128; t0+=4){
        #pragma unroll
        for (int k=0;k<4;k++){
            const int t = t0 + k;
            const int m = m0 + t;
            // consume stage k
            float uv = uvp[k], zv = zvp[k];
            float4 P0=Pp[k][0], P1=Pp[k][1], P2=Pp[k][2], P3=Pp[k][3], P4=Pp[k][4],
                   P5=Pp[k][5], P6=Pp[k][6], P7=Pp[k][7], P8=Pp[k][8], P9=Pp[k][9];
            // refill stage k with t+4 (clamped; values unused past end)
            const int mf = m0 + ((t+4 < 128) ? (t+4) : 127);
            uvp[k] = U[(size_t)mf*256 + d];
            zvp[k] = xz[(size_t)mf*512 + 256 + d];
            #pragma unroll
            for (int q=0;q<10;q++) Pp[k][q] = *(const float4*)&proj[(size_t)mf*40 + q*4];
            // compute step t
            float dt = dtbv;
            dt = fmaf(P0.x,dw0.x,fmaf(P0.y,dw0.y,fmaf(P0.z,dw0.z,fmaf(P0.w,dw0.w,dt))));
            dt = fmaf(P1.x,dw1.x,fmaf(P1.y,dw1.y,fmaf(P1.z,dw1.z,fmaf(P1.w,dw1.w,dt))));
            float dv = softplusf(dt);
            float du = dv*uv;
            const float Bv[16] = {P2.x,P2.y,P2.z,P2.w, P3.x,P3.y,P3.z,P3.w,
                                  P4.x,P4.y,P4.z,P4.w, P5.x,P5.y,P5.z,P5.w};
            const float Cv[16] = {P6.x,P6.y,P6.z,P6.w, P7.x,P7.y,P7.z,P7.w,
                                  P8.x,P8.y,P8.z,P8.w, P9.x,P9.y,P9.z,P9.w};
            float y = 0.f;
            #pragma unroll
            for (int s=0;s<16;s++){
                float dA = __expf(dv*A[s]);
                h[s] = fmaf(dA, h[s], du*Bv[s]);
                y = fmaf(h[s], Cv[s], y);
            }
            U[(size_t)m*256 + d] = (y + uv*Dv) * siluf(zv);
        }
    }
}

// ---------------------------------------------------------------------------
// feats[c,h,w] -> out[w*ows + h*ohs + c]   (per-h 128x128 transpose)
__global__ __launch_bounds__(256) void transpose_cw_kernel(
    const float* __restrict__ feats, float* __restrict__ out,
    int ows, int ohs)
{
    __shared__ float tile[32][33];
    const int h = blockIdx.z;
    const int c0 = blockIdx.y*32, w0 = blockIdx.x*32;
    const int lx = threadIdx.x & 31, ly = threadIdx.x >> 5;
    #pragma unroll
    for (int i=0;i<4;i++){
        int c = c0 + ly + i*8;
        tile[ly+i*8][lx] = feats[(size_t)c*16384 + h*128 + w0 + lx];
    }
    __syncthreads();
    #pragma unroll
    for (int i=0;i<4;i++){
        int w = w0 + ly + i*8;
        out[(size_t)w*ows + (size_t)h*ohs + c0 + lx] = tile[lx][ly+i*8];
    }
}

// FH[c,h,w] = XH[w,h,c] + XW[h,w,c]
__global__ __launch_bounds__(256) void fuse_transpose_kernel(
    const float* __restrict__ XH, const float* __restrict__ XW,
    float* __restrict__ FH)
{
    __shared__ float tile[32][33];
    const int h = blockIdx.z;
    const int c0 = blockIdx.y*32, w0 = blockIdx.x*32;
    const int lx = threadIdx.x & 31, ly = threadIdx.x >> 5;
    #pragma unroll
    for (int i=0;i<4;i++){
        int w = w0 + ly + i*8;
        float v = XH[(size_t)w*16384 + h*128 + c0 + lx]
                + XW[(size_t)h*16384 + w*128 + c0 + lx];
        tile[ly+i*8][lx] = v;
    }
    __syncthreads();
    #pragma unroll
    for (int i=0;i<4;i++){
        int c = c0 + ly + i*8;
        FH[(size_t)c*16384 + h*128 + w0 + lx] = tile[lx][ly+i*8];
    }
}

// ---------------------------------------------------------------------------
extern "C" void kernel_launch(void* const* d_in, const int* in_sizes, int n_in,
                              void* d_out, int out_size, void* d_ws, size_t ws_size,
                              hipStream_t stream)
{
    const float* x        = (const float*)d_in[0];
    const float* enc1_w   = (const float*)d_in[1];
    const float* enc1_b   = (const float*)d_in[2];
    const float* enc2_w   = (const float*)d_in[3];
    const float* enc2_b   = (const float*)d_in[4];
    const float* m_in_w   = (const float*)d_in[5];
    const float* m_conv_w = (const float*)d_in[6];
    const float* m_conv_b = (const float*)d_in[7];
    const float* m_xproj_w= (const float*)d_in[8];
    const float* m_dt_w   = (const float*)d_in[9];
    const float* m_dt_b   = (const float*)d_in[10];
    const float* m_Alog   = (const float*)d_in[11];
    const float* m_D      = (const float*)d_in[12];
    const float* m_out_w  = (const float*)d_in[13];
    const float* fus_w    = (const float*)d_in[14];
    const float* fus_b    = (const float*)d_in[15];
    const float* pred1_w  = (const float*)d_in[16];
    const float* pred1_b  = (const float*)d_in[17];
    const float* pred2_w  = (const float*)d_in[18];
    const float* pred2_b  = (const float*)d_in[19];
    float* out = (float*)d_out;

    float* ws    = (float*)d_ws;
    float* FEATS = ws;                         // 2M floats
    float* XH    = ws +  2u*1024*1024;         // 2M
    float* XW    = ws +  4u*1024*1024;         // 2M
    float* XZ    = ws +  6u*1024*1024;         // 8M  [NTOK,512]
    float* U     = ws + 14u*1024*1024;         // 4M  [NTOK,256]
    float* PROJ  = ws + 18u*1024*1024;         // 640K [NTOK,40]
    // liveness-based aliases within XZ (dead outside the mamba stacks):
    float* T0 = XZ;                  // conv1 output
    float* FH = XZ;                  // feats_h + feats_w
    float* G1 = XZ + 2u*1024*1024;   // fus conv output
    float* G2 = XZ + 4u*1024*1024;   // pred1 output
    // pre-split conv weights (bf16 hi/lo, 147456 ushorts each):
    unsigned short* EHI = (unsigned short*)(ws + 10u*1024*1024);
    unsigned short* ELO = EHI + 147456;
    unsigned short* FHI = (unsigned short*)(ws + 12u*1024*1024);
    unsigned short* FLO = FHI + 147456;
    unsigned short* PHI = FLO + 147456;
    unsigned short* PLO = PHI + 147456;

    const dim3 cmgrid(8, 32, 2);   // conv_mfma: 512 blocks

    // encoder
    conv3x3_kernel<true ><<<dim3(2,8,16), 256, 0, stream>>>(x, enc1_w, enc1_b, T0, 1, 128);
    wsplit_kernel<<<576, 256, 0, stream>>>(enc2_w, EHI, ELO);
    conv_mfma_kernel<false><<<cmgrid, 256, 0, stream>>>(T0, EHI, ELO, enc2_b, FEATS);

    // layouts for the two scan directions
    transpose_cw_kernel<<<dim3(4,4,128), 256, 0, stream>>>(FEATS, XH, 16384, 128); // [w,h,c]
    transpose_cw_kernel<<<dim3(4,4,128), 256, 0, stream>>>(FEATS, XW, 128, 16384); // [h,w,c]

    for (int pass = 0; pass < 2; pass++){
        float* Xact = pass ? XW : XH;
        for (int l = 0; l < 3; l++){
            gemm_mfma_kernel<<<dim3(256,8), 256, 0, stream>>>(Xact, m_in_w + (size_t)l*512*128, XZ, NTOK, 512, 128);
            conv1d_silu_kernel<<<NTOK, 256, 0, stream>>>(XZ, m_conv_w + (size_t)l*256*4, m_conv_b + (size_t)l*256, U);
            gemm_mfma_kernel<<<dim3(256,1), 256, 0, stream>>>(U, m_xproj_w + (size_t)l*40*256, PROJ, NTOK, 40, 256);
            scan_fused_kernel<<<dim3(4,128), 64, 0, stream>>>(XZ, U, PROJ,
                m_dt_w + (size_t)l*256*8, m_dt_b + (size_t)l*256,
                m_Alog + (size_t)l*256*16, m_D + (size_t)l*256);
            gemm_mfma_kernel<<<dim3(256,2), 256, 0, stream>>>(U, m_out_w + (size_t)l*128*256, Xact, NTOK, 128, 256);
        }
    }

    fuse_transpose_kernel<<<dim3(4,4,128), 256, 0, stream>>>(XH, XW, FH);

    // decoder
    wsplit_kernel<<<576, 256, 0, stream>>>(fus_w, FHI, FLO);
    conv_mfma_kernel<false><<<cmgrid, 256, 0, stream>>>(FH, FHI, FLO, fus_b, G1);
    wsplit_kernel<<<576, 256, 0, stream>>>(pred1_w, PHI, PLO);
    conv_mfma_kernel<true ><<<cmgrid, 256, 0, stream>>>(G1, PHI, PLO, pred1_b, G2);
    conv3x3_co1_kernel<<<64, 256, 0, stream>>>(G2, pred2_w, pred2_b, out, 128);
}

// Round 10
// 1140.377 us; speedup vs baseline: 1.4484x; 1.4484x over previous
//
#include <hip/hip_runtime.h>
#include <math.h>

#define NTOK 16384   // 128 sequences * 128 steps

typedef __attribute__((ext_vector_type(8))) short bf16x8;
typedef __attribute__((ext_vector_type(4))) float f32x4;

__device__ __forceinline__ float geluf(float x){
    return 0.5f*x*(1.0f+erff(x*0.70710678118654752f));
}
__device__ __forceinline__ float siluf(float x){
    return x/(1.0f+__expf(-x));
}
__device__ __forceinline__ float softplusf(float x){
    return (x>20.0f)? x : log1pf(__expf(x));
}
__device__ __forceinline__ void split_bf16(float x, unsigned short& h, unsigned short& l){
    union { float f; unsigned u; } c; c.f = x;
    h = (unsigned short)(c.u >> 16);
    union { unsigned u; float f; } hf; hf.u = c.u & 0xffff0000u;
    union { float f; unsigned u; } rc; rc.f = x - hf.f;
    l = (unsigned short)(rc.u >> 16);
}

// ---------------------------------------------------------------------------
// enc1 conv (CI=1), original structure - cheap, leave alone.
template<bool GELU_OUT>
__global__ __launch_bounds__(256) void conv3x3_kernel(
    const float* __restrict__ in, const float* __restrict__ wgt,
    const float* __restrict__ bias, float* __restrict__ out,
    int CI, int CO)
{
    __shared__ float tile[18][68];
    const int tx = threadIdx.x & 15;
    const int ty = threadIdx.x >> 4;
    const int w0 = blockIdx.x * 64;
    const int h0 = blockIdx.y * 16;
    const int cog = blockIdx.z * 8;

    float acc[8][4];
    #pragma unroll
    for (int i=0;i<8;i++){
        float b = (cog+i < CO) ? bias[cog+i] : 0.f;
        #pragma unroll
        for (int j=0;j<4;j++) acc[i][j] = b;
    }

    for (int ci=0; ci<CI; ci++){
        const float* inp = in + ci*16384;
        for (int e = threadIdx.x; e < 18*66; e += 256){
            int r = e/66, cc = e - r*66;
            int hh = h0 - 1 + r, ww = w0 - 1 + cc;
            float v = 0.f;
            if ((unsigned)hh < 128u && (unsigned)ww < 128u) v = inp[hh*128+ww];
            tile[r][cc] = v;
        }
        __syncthreads();
        float rin[3][8];
        #pragma unroll
        for (int r=0;r<3;r++){
            float4 a = *(const float4*)&tile[ty+r][tx*4];
            float4 b = *(const float4*)&tile[ty+r][tx*4+4];
            rin[r][0]=a.x; rin[r][1]=a.y; rin[r][2]=a.z; rin[r][3]=a.w;
            rin[r][4]=b.x; rin[r][5]=b.y; rin[r][6]=b.z; rin[r][7]=b.w;
        }
        #pragma unroll
        for (int co=0; co<8; co++){
            if (cog+co < CO) {
                const float* wp = wgt + ((cog+co)*CI + ci)*9;
                #pragma unroll
                for (int r=0;r<3;r++){
                    #pragma unroll
                    for (int dx=0;dx<3;dx++){
                        float wv = wp[r*3+dx];
                        #pragma unroll
                        for (int j=0;j<4;j++)
                            acc[co][j] = fmaf(wv, rin[r][j+dx], acc[co][j]);
                    }
                }
            }
        }
        __syncthreads();
    }
    const int h = h0 + ty;
    const int wbase = w0 + tx*4;
    #pragma unroll
    for (int co=0; co<8; co++){
        if (cog+co < CO){
            float t0 = acc[co][0], t1 = acc[co][1], t2 = acc[co][2], t3 = acc[co][3];
            if (GELU_OUT){ t0=geluf(t0); t1=geluf(t1); t2=geluf(t2); t3=geluf(t3); }
            *(float4*)&out[(cog+co)*16384 + h*128 + wbase] = make_float4(t0,t1,t2,t3);
        }
    }
}

// ---------------------------------------------------------------------------
// weight split prepass: wgt [128co][128ci][3][3] f32 -> hi/lo bf16 in
// fragment-major layout [t][cog8][chunk4][kg4][lr16][j8].
__global__ __launch_bounds__(256) void wsplit_kernel(
    const float* __restrict__ wgt, unsigned short* __restrict__ whi,
    unsigned short* __restrict__ wlo)
{
    int e = blockIdx.x*256 + threadIdx.x;   // < 147456
    int ci = e & 127, co = (e >> 7) & 127, t = e >> 14;
    float v = wgt[((co<<7)|ci)*9 + t];
    unsigned short h, l; split_bf16(v, h, l);
    int cog = co >> 4, lr = co & 15;
    int chk = ci >> 5, kg = (ci >> 3) & 3, j = ci & 7;
    int o = ((((t*8 + cog)*4 + chk)*4 + kg)*16 + lr)*8 + j;
    whi[o] = h; wlo[o] = l;
}

// ---------------------------------------------------------------------------
// conv2d 3x3 as 9-tap split-bf16 MFMA GEMM. CI=CO=128 fixed.
template<bool GELU_OUT>
__global__ __launch_bounds__(256) void conv_mfma_kernel(
    const float* __restrict__ in, const unsigned short* __restrict__ whi,
    const unsigned short* __restrict__ wlo, const float* __restrict__ bias,
    float* __restrict__ out)
{
    __shared__ unsigned short sHi[6*20*40], sLo[6*20*40];
    const int tid  = threadIdx.x;
    const int wave = tid >> 6;
    const int lane = tid & 63;
    const int wr   = wave >> 1;
    const int wc   = wave & 1;
    const int lr   = lane & 15;
    const int kg   = lane >> 4;
    const int w0   = blockIdx.x * 16;
    const int h0   = blockIdx.y * 4;
    const int cogz = blockIdx.z * 4;

    f32x4 acc[2][2];
    #pragma unroll
    for (int cg=0;cg<2;cg++)
        #pragma unroll
        for (int pg=0;pg<2;pg++)
            acc[cg][pg] = (f32x4){0.f,0.f,0.f,0.f};

    for (int ch = 0; ch < 4; ch++){
        const int cc0 = ch*32;
        for (int e = tid; e < 3456; e += 256){
            int cil = e / 108;
            int rem = e - cil*108;
            int hl  = rem / 18;
            int wl  = rem - hl*18;
            int hh = h0 - 1 + hl, ww = w0 - 1 + wl;
            float v = 0.f;
            if ((unsigned)hh < 128u && (unsigned)ww < 128u)
                v = in[(size_t)(cc0+cil)*16384 + hh*128 + ww];
            unsigned short hi, lo; split_bf16(v, hi, lo);
            int o = (hl*20 + wl)*40 + cil;
            sHi[o] = hi; sLo[o] = lo;
        }
        __syncthreads();
        #pragma unroll
        for (int dy=0; dy<3; dy++){
            #pragma unroll
            for (int dx=0; dx<3; dx++){
                const int t = dy*3+dx;
                bf16x8 ah[2], al[2], bh[2], bl[2];
                #pragma unroll
                for (int cg=0; cg<2; cg++){
                    int cog = cogz + wr*2 + cg;
                    size_t off = ((size_t)(((t*8 + cog)*4 + ch)*4 + kg)*16 + lr)*8;
                    ah[cg] = *(const bf16x8*)&whi[off];
                    al[cg] = *(const bf16x8*)&wlo[off];
                }
                #pragma unroll
                for (int pg=0; pg<2; pg++){
                    int g = wc*2 + pg;
                    int o = ((g+dy)*20 + lr + dx)*40 + kg*8;
                    bh[pg] = *(const bf16x8*)&sHi[o];
                    bl[pg] = *(const bf16x8*)&sLo[o];
                }
                #pragma unroll
                for (int cg=0; cg<2; cg++){
                    #pragma unroll
                    for (int pg=0; pg<2; pg++){
                        acc[cg][pg] = __builtin_amdgcn_mfma_f32_16x16x32_bf16(ah[cg], bh[pg], acc[cg][pg], 0,0,0);
                        acc[cg][pg] = __builtin_amdgcn_mfma_f32_16x16x32_bf16(ah[cg], bl[pg], acc[cg][pg], 0,0,0);
                        acc[cg][pg] = __builtin_amdgcn_mfma_f32_16x16x32_bf16(al[cg], bh[pg], acc[cg][pg], 0,0,0);
                    }
                }
            }
        }
        __syncthreads();
    }
    #pragma unroll
    for (int cg=0; cg<2; cg++){
        #pragma unroll
        for (int pg=0; pg<2; pg++){
            int h = h0 + wc*2 + pg;
            int w = w0 + lr;
            #pragma unroll
            for (int r=0; r<4; r++){
                int co = (cogz + wr*2 + cg)*16 + kg*4 + r;
                float v = acc[cg][pg][r] + bias[co];
                if (GELU_OUT) v = geluf(v);
                out[(size_t)co*16384 + h*128 + w] = v;
            }
        }
    }
}

// ---------------------------------------------------------------------------
// CO=1 conv (pred2). grid 64 blocks, block = 2 h-rows x 128 w.
__global__ __launch_bounds__(256) void conv3x3_co1_kernel(
    const float* __restrict__ in, const float* __restrict__ wgt,
    const float* __restrict__ bias, float* __restrict__ out, int CI)
{
    __shared__ float tile[16][4][128];
    const int h0 = blockIdx.x*2;
    const int hl = threadIdx.x >> 7;      // 0..1
    const int w  = threadIdx.x & 127;
    float acc = bias[0];
    for (int cc0 = 0; cc0 < CI; cc0 += 16){
        for (int e = threadIdx.x; e < 2048; e += 256){
            int c4 = e & 31, r = (e>>5)&3, ci = e>>7;
            int hh = h0 - 1 + r;
            float4 v = make_float4(0.f,0.f,0.f,0.f);
            if ((unsigned)hh < 128u)
                v = *(const float4*)&in[(size_t)(cc0+ci)*16384 + hh*128 + c4*4];
            *(float4*)&tile[ci][r][c4*4] = v;
        }
        __syncthreads();
        #pragma unroll 4
        for (int ci=0; ci<16; ci++){
            float w_s[9];
            #pragma unroll
            for (int k=0;k<9;k++) w_s[k] = wgt[(size_t)(cc0+ci)*9 + k];
            #pragma unroll
            for (int r=0;r<3;r++){
                #pragma unroll
                for (int dx=0;dx<3;dx++){
                    int col = w + dx - 1;
                    float x = ((unsigned)col < 128u) ? tile[ci][hl+r][col] : 0.f;
                    acc = fmaf(w_s[r*3+dx], x, acc);
                }
            }
        }
        __syncthreads();
    }
    out[(size_t)(h0+hl)*128 + w] = acc;
}

// ---------------------------------------------------------------------------
// Split-bf16 MFMA GEMM: C[M,N] = A[M,K] * W[N,K]^T in ~fp32 precision.
__global__ __launch_bounds__(256) void gemm_mfma_kernel(
    const float* __restrict__ A, const float* __restrict__ W,
    float* __restrict__ C, int M, int N, int K)
{
    __shared__ unsigned short Ah[64*48], Al[64*48], Bh[64*48], Bl[64*48];
    const int tid  = threadIdx.x;
    const int wave = tid >> 6;
    const int lane = tid & 63;
    const int wr   = wave >> 1;
    const int wc   = wave & 1;
    const int lrow = lane & 15;
    const int kg   = lane >> 4;

    const int m0 = blockIdx.x * 64;
    const int n0 = blockIdx.y * 64;

    f32x4 acc[2][2];
    #pragma unroll
    for (int mi=0;mi<2;mi++)
        #pragma unroll
        for (int ni=0;ni<2;ni++)
            acc[mi][ni] = (f32x4){0.f,0.f,0.f,0.f};

    for (int k0 = 0; k0 < K; k0 += 32){
        #pragma unroll
        for (int it=0; it<2; it++){
            int idx = tid + it*256;
            int r = idx >> 3, c4 = idx & 7;
            float4 v = *(const float4*)&A[(size_t)(m0+r)*K + k0 + c4*4];
            unsigned short h[4], l[4];
            split_bf16(v.x, h[0], l[0]);
            split_bf16(v.y, h[1], l[1]);
            split_bf16(v.z, h[2], l[2]);
            split_bf16(v.w, h[3], l[3]);
            *(uint2*)&Ah[r*48 + c4*4] = make_uint2(h[0]|((unsigned)h[1]<<16), h[2]|((unsigned)h[3]<<16));
            *(uint2*)&Al[r*48 + c4*4] = make_uint2(l[0]|((unsigned)l[1]<<16), l[2]|((unsigned)l[3]<<16));
        }
        #pragma unroll
        for (int it=0; it<2; it++){
            int idx = tid + it*256;
            int r = idx >> 3, c4 = idx & 7;
            float4 v = make_float4(0.f,0.f,0.f,0.f);
            if (n0 + r < N) v = *(const float4*)&W[(size_t)(n0+r)*K + k0 + c4*4];
            unsigned short h[4], l[4];
            split_bf16(v.x, h[0], l[0]);
            split_bf16(v.y, h[1], l[1]);
            split_bf16(v.z, h[2], l[2]);
            split_bf16(v.w, h[3], l[3]);
            *(uint2*)&Bh[r*48 + c4*4] = make_uint2(h[0]|((unsigned)h[1]<<16), h[2]|((unsigned)h[3]<<16));
            *(uint2*)&Bl[r*48 + c4*4] = make_uint2(l[0]|((unsigned)l[1]<<16), l[2]|((unsigned)l[3]<<16));
        }
        __syncthreads();

        bf16x8 fah[2], fal[2], fbh[2], fbl[2];
        #pragma unroll
        for (int mi=0;mi<2;mi++){
            int row = (wr*2+mi)*16 + lrow;
            fah[mi] = *(const bf16x8*)&Ah[row*48 + kg*8];
            fal[mi] = *(const bf16x8*)&Al[row*48 + kg*8];
        }
        #pragma unroll
        for (int ni=0;ni<2;ni++){
            int row = (wc*2+ni)*16 + lrow;
            fbh[ni] = *(const bf16x8*)&Bh[row*48 + kg*8];
            fbl[ni] = *(const bf16x8*)&Bl[row*48 + kg*8];
        }
        #pragma unroll
        for (int mi=0;mi<2;mi++){
            #pragma unroll
            for (int ni=0;ni<2;ni++){
                acc[mi][ni] = __builtin_amdgcn_mfma_f32_16x16x32_bf16(fah[mi], fbh[ni], acc[mi][ni], 0,0,0);
                acc[mi][ni] = __builtin_amdgcn_mfma_f32_16x16x32_bf16(fah[mi], fbl[ni], acc[mi][ni], 0,0,0);
                acc[mi][ni] = __builtin_amdgcn_mfma_f32_16x16x32_bf16(fal[mi], fbh[ni], acc[mi][ni], 0,0,0);
            }
        }
        __syncthreads();
    }
    #pragma unroll
    for (int mi=0;mi<2;mi++){
        #pragma unroll
        for (int ni=0;ni<2;ni++){
            int n = n0 + (wc*2+ni)*16 + lrow;
            if (n < N){
                #pragma unroll
                for (int r=0;r<4;r++){
                    int m = m0 + (wr*2+mi)*16 + kg*4 + r;
                    C[(size_t)m*N + n] = acc[mi][ni][r];
                }
            }
        }
    }
}

// ---------------------------------------------------------------------------
// depthwise causal conv1d (k=4) + silu.  xz [NTOK,512] (xs = cols 0..255)
__global__ __launch_bounds__(256) void conv1d_silu_kernel(
    const float* __restrict__ xz, const float* __restrict__ cw,
    const float* __restrict__ cb, float* __restrict__ U)
{
    const int m = blockIdx.x;
    const int d = threadIdx.x;
    const int t = m & 127;
    float4 w4 = *(const float4*)&cw[d*4];
    float wj[4] = {w4.x, w4.y, w4.z, w4.w};
    float s = cb[d];
    #pragma unroll
    for (int j=0;j<4;j++){
        int tt = t - 3 + j;
        if (tt >= 0) s = fmaf(wj[j], xz[(size_t)(m - 3 + j)*512 + d], s);
    }
    U[(size_t)m*256 + d] = siluf(s);
}

// ---------------------------------------------------------------------------
// fused scan, proj staged in LDS. grid (4,128), 64 thr/block.
// Within a block the proj row address is lane-invariant, so the whole
// sequence's proj block (128 rows x 40 f32 = 20KB) is cooperatively staged
// into LDS once (coalesced, L2-resident source), then read per-iteration as
// ds_read_b128 broadcasts (~120cy, conflict-free) instead of ~900cy HBM
// loads. Round-9 lesson: a register prefetch ring this large spills (VGPR=48
// observed); LDS sidesteps the allocator. u/z keep a tiny 4-deep ring (8 VGPR).
__global__ __launch_bounds__(64) void scan_fused_kernel(
    const float* __restrict__ xz, float* __restrict__ U,
    const float* __restrict__ proj, const float* __restrict__ dtw,
    const float* __restrict__ dtb, const float* __restrict__ Alog,
    const float* __restrict__ Dp)
{
    __shared__ float sP[128*40];
    const int b = blockIdx.y;
    const int d = blockIdx.x*64 + threadIdx.x;

    // cooperative stage: 1280 float4
    {
        const float4* src = (const float4*)(proj + (size_t)b*128*40);
        float4* dst = (float4*)sP;
        #pragma unroll
        for (int i=0;i<20;i++)
            dst[threadIdx.x + i*64] = src[threadIdx.x + i*64];
    }

    float A[16], h[16];
    #pragma unroll
    for (int s=0;s<16;s++){ A[s] = -__expf(Alog[d*16+s]); h[s]=0.f; }
    float4 dw0 = *(const float4*)&dtw[d*8];
    float4 dw1 = *(const float4*)&dtw[d*8+4];
    const float dtbv = dtb[d];
    const float Dv = Dp[d];
    const int m0 = b*128;

    // 4-deep u/z register ring (small: 8 VGPRs)
    float uvp[4], zvp[4];
    #pragma unroll
    for (int k=0;k<4;k++){
        int m = m0 + k;
        uvp[k] = U[(size_t)m*256 + d];
        zvp[k] = xz[(size_t)m*512 + 256 + d];
    }
    __syncthreads();

    for (int t0=0; t0<128; t0+=4){
        #pragma unroll
        for (int k=0;k<4;k++){
            const int t = t0 + k;
            const int m = m0 + t;
            float uv = uvp[k], zv = zvp[k];
            const int mf = m0 + ((t+4 < 128) ? (t+4) : 127);
            uvp[k] = U[(size_t)mf*256 + d];
            zvp[k] = xz[(size_t)mf*512 + 256 + d];

            const float* p = &sP[t*40];
            float4 P0 = *(const float4*)(p);
            float4 P1 = *(const float4*)(p+4);
            float dt = dtbv;
            dt = fmaf(P0.x,dw0.x,fmaf(P0.y,dw0.y,fmaf(P0.z,dw0.z,fmaf(P0.w,dw0.w,dt))));
            dt = fmaf(P1.x,dw1.x,fmaf(P1.y,dw1.y,fmaf(P1.z,dw1.z,fmaf(P1.w,dw1.w,dt))));
            float dv = softplusf(dt);
            float du = dv*uv;
            float4 B0 = *(const float4*)(p+8),  B1 = *(const float4*)(p+12),
                   B2 = *(const float4*)(p+16), B3 = *(const float4*)(p+20);
            float4 C0 = *(const float4*)(p+24), C1 = *(const float4*)(p+28),
                   C2 = *(const float4*)(p+32), C3 = *(const float4*)(p+36);
            const float Bv[16] = {B0.x,B0.y,B0.z,B0.w, B1.x,B1.y,B1.z,B1.w,
                                  B2.x,B2.y,B2.z,B2.w, B3.x,B3.y,B3.z,B3.w};
            const float Cv[16] = {C0.x,C0.y,C0.z,C0.w, C1.x,C1.y,C1.z,C1.w,
                                  C2.x,C2.y,C2.z,C2.w, C3.x,C3.y,C3.z,C3.w};
            float y = 0.f;
            #pragma unroll
            for (int s=0;s<16;s++){
                float dA = __expf(dv*A[s]);
                h[s] = fmaf(dA, h[s], du*Bv[s]);
                y = fmaf(h[s], Cv[s], y);
            }
            U[(size_t)m*256 + d] = (y + uv*Dv) * siluf(zv);
        }
    }
}

// ---------------------------------------------------------------------------
// feats[c,h,w] -> out[w*ows + h*ohs + c]   (per-h 128x128 transpose)
__global__ __launch_bounds__(256) void transpose_cw_kernel(
    const float* __restrict__ feats, float* __restrict__ out,
    int ows, int ohs)
{
    __shared__ float tile[32][33];
    const int h = blockIdx.z;
    const int c0 = blockIdx.y*32, w0 = blockIdx.x*32;
    const int lx = threadIdx.x & 31, ly = threadIdx.x >> 5;
    #pragma unroll
    for (int i=0;i<4;i++){
        int c = c0 + ly + i*8;
        tile[ly+i*8][lx] = feats[(size_t)c*16384 + h*128 + w0 + lx];
    }
    __syncthreads();
    #pragma unroll
    for (int i=0;i<4;i++){
        int w = w0 + ly + i*8;
        out[(size_t)w*ows + (size_t)h*ohs + c0 + lx] = tile[lx][ly+i*8];
    }
}

// FH[c,h,w] = XH[w,h,c] + XW[h,w,c]
__global__ __launch_bounds__(256) void fuse_transpose_kernel(
    const float* __restrict__ XH, const float* __restrict__ XW,
    float* __restrict__ FH)
{
    __shared__ float tile[32][33];
    const int h = blockIdx.z;
    const int c0 = blockIdx.y*32, w0 = blockIdx.x*32;
    const int lx = threadIdx.x & 31, ly = threadIdx.x >> 5;
    #pragma unroll
    for (int i=0;i<4;i++){
        int w = w0 + ly + i*8;
        float v = XH[(size_t)w*16384 + h*128 + c0 + lx]
                + XW[(size_t)h*16384 + w*128 + c0 + lx];
        tile[ly+i*8][lx] = v;
    }
    __syncthreads();
    #pragma unroll
    for (int i=0;i<4;i++){
        int c = c0 + ly + i*8;
        FH[(size_t)c*16384 + h*128 + w0 + lx] = tile[lx][ly+i*8];
    }
}

// ---------------------------------------------------------------------------
extern "C" void kernel_launch(void* const* d_in, const int* in_sizes, int n_in,
                              void* d_out, int out_size, void* d_ws, size_t ws_size,
                              hipStream_t stream)
{
    const float* x        = (const float*)d_in[0];
    const float* enc1_w   = (const float*)d_in[1];
    const float* enc1_b   = (const float*)d_in[2];
    const float* enc2_w   = (const float*)d_in[3];
    const float* enc2_b   = (const float*)d_in[4];
    const float* m_in_w   = (const float*)d_in[5];
    const float* m_conv_w = (const float*)d_in[6];
    const float* m_conv_b = (const float*)d_in[7];
    const float* m_xproj_w= (const float*)d_in[8];
    const float* m_dt_w   = (const float*)d_in[9];
    const float* m_dt_b   = (const float*)d_in[10];
    const float* m_Alog   = (const float*)d_in[11];
    const float* m_D      = (const float*)d_in[12];
    const float* m_out_w  = (const float*)d_in[13];
    const float* fus_w    = (const float*)d_in[14];
    const float* fus_b    = (const float*)d_in[15];
    const float* pred1_w  = (const float*)d_in[16];
    const float* pred1_b  = (const float*)d_in[17];
    const float* pred2_w  = (const float*)d_in[18];
    const float* pred2_b  = (const float*)d_in[19];
    float* out = (float*)d_out;

    float* ws    = (float*)d_ws;
    float* FEATS = ws;                         // 2M floats
    float* XH    = ws +  2u*1024*1024;         // 2M
    float* XW    = ws +  4u*1024*1024;         // 2M
    float* XZ    = ws +  6u*1024*1024;         // 8M  [NTOK,512]
    float* U     = ws + 14u*1024*1024;         // 4M  [NTOK,256]
    float* PROJ  = ws + 18u*1024*1024;         // 640K [NTOK,40]
    // liveness-based aliases within XZ (dead outside the mamba stacks):
    float* T0 = XZ;                  // conv1 output
    float* FH = XZ;                  // feats_h + feats_w
    float* G1 = XZ + 2u*1024*1024;   // fus conv output
    float* G2 = XZ + 4u*1024*1024;   // pred1 output
    // pre-split conv weights (bf16 hi/lo, 147456 ushorts each):
    unsigned short* EHI = (unsigned short*)(ws + 10u*1024*1024);
    unsigned short* ELO = EHI + 147456;
    unsigned short* FHI = (unsigned short*)(ws + 12u*1024*1024);
    unsigned short* FLO = FHI + 147456;
    unsigned short* PHI = FLO + 147456;
    unsigned short* PLO = PHI + 147456;

    const dim3 cmgrid(8, 32, 2);   // conv_mfma: 512 blocks

    // encoder
    conv3x3_kernel<true ><<<dim3(2,8,16), 256, 0, stream>>>(x, enc1_w, enc1_b, T0, 1, 128);
    wsplit_kernel<<<576, 256, 0, stream>>>(enc2_w, EHI, ELO);
    conv_mfma_kernel<false><<<cmgrid, 256, 0, stream>>>(T0, EHI, ELO, enc2_b, FEATS);

    // layouts for the two scan directions
    transpose_cw_kernel<<<dim3(4,4,128), 256, 0, stream>>>(FEATS, XH, 16384, 128); // [w,h,c]
    transpose_cw_kernel<<<dim3(4,4,128), 256, 0, stream>>>(FEATS, XW, 128, 16384); // [h,w,c]

    for (int pass = 0; pass < 2; pass++){
        float* Xact = pass ? XW : XH;
        for (int l = 0; l < 3; l++){
            gemm_mfma_kernel<<<dim3(256,8), 256, 0, stream>>>(Xact, m_in_w + (size_t)l*512*128, XZ, NTOK, 512, 128);
            conv1d_silu_kernel<<<NTOK, 256, 0, stream>>>(XZ, m_conv_w + (size_t)l*256*4, m_conv_b + (size_t)l*256, U);
            gemm_mfma_kernel<<<dim3(256,1), 256, 0, stream>>>(U, m_xproj_w + (size_t)l*40*256, PROJ, NTOK, 40, 256);
            scan_fused_kernel<<<dim3(4,128), 64, 0, stream>>>(XZ, U, PROJ,
                m_dt_w + (size_t)l*256*8, m_dt_b + (size_t)l*256,
                m_Alog + (size_t)l*256*16, m_D + (size_t)l*256);
            gemm_mfma_kernel<<<dim3(256,2), 256, 0, stream>>>(U, m_out_w + (size_t)l*128*256, Xact, NTOK, 128, 256);
        }
    }

    fuse_transpose_kernel<<<dim3(4,4,128), 256, 0, stream>>>(XH, XW, FH);

    // decoder
    wsplit_kernel<<<576, 256, 0, stream>>>(fus_w, FHI, FLO);
    conv_mfma_kernel<false><<<cmgrid, 256, 0, stream>>>(FH, FHI, FLO, fus_b, G1);
    wsplit_kernel<<<576, 256, 0, stream>>>(pred1_w, PHI, PLO);
    conv_mfma_kernel<true ><<<cmgrid, 256, 0, stream>>>(G1, PHI, PLO, pred1_b, G2);
    conv3x3_co1_kernel<<<64, 256, 0, stream>>>(G2, pred2_w, pred2_b, out, 128);
}